// Round 5
// baseline (406.019 us; speedup 1.0000x reference)
//
#include <hip/hip_runtime.h>
#include <hip/hip_bf16.h>
#include <math.h>

#define N_B 32
#define T_S 512
#define D_D 1024
#define C_C 120
#define ZB 96           // 3 streams x 32 batch rows
#define SCALE 64.0f     // 2*sqrt(1024)

typedef unsigned short u16;
typedef __attribute__((ext_vector_type(8))) short short8;
typedef __attribute__((ext_vector_type(8))) unsigned short ushort8;
typedef __attribute__((ext_vector_type(4))) float floatx4;

__device__ inline u16 f2bf(float f) {
    union { __hip_bfloat16 h; u16 u; } c; c.h = __float2bfloat16(f); return c.u;
}
__device__ inline float bf2f(u16 u) {
    union { unsigned i; float f; } c; c.i = ((unsigned)u) << 16; return c.f;
}

// async global->LDS, 16B per lane. LDS dest = wave-uniform base + lane*16.
__device__ inline void gll16(const void* g, void* l) {
    __builtin_amdgcn_global_load_lds((const __attribute__((address_space(1))) void*)g,
                                     (__attribute__((address_space(3))) void*)l,
                                     16, 0, 0);
}

// ---- mask dtype robustness: harness may deliver bool as int32 or int8 ----
__device__ inline bool mask_is_i8(const int* mk) {
    bool i8 = false;
#pragma unroll
    for (int i = 0; i < 16; i++) {
        unsigned v = ((const unsigned*)mk)[i];
        if (v > 1u) i8 = true;
    }
    return i8;
}
__device__ inline int mask_val(const int* mk, int idx, bool i8) {
    return i8 ? (int)((const signed char*)mk)[idx] : mk[idx];
}

// ==== k_scan: every block redundantly counts ALL 96 zb rows (ballots) so it
// can derive its own zb's GLOBAL packed base (pad-64) with no cross-block dep.
// Writes slotbase (global, per chunk), cnts, gb, zblk (64-row-block -> zb map),
// mtot; zeroes per-zb pad rows, global 256-pad (xp rows, attnw, zblk) and the
// 2MB accumulator region. 96 blocks x 256 threads.
__global__ void k_scan(const int* m0, const int* m1, const int* m2,
                       int* __restrict__ slotbase, int* __restrict__ cnts,
                       int* __restrict__ gb, int* __restrict__ zblk,
                       int* __restrict__ mtot, u16* __restrict__ xp,
                       float* __restrict__ attnw, float4* __restrict__ zreg) {
    int zb = blockIdx.x;
    int tid = threadIdx.x;
    // zero accumulators (xsum/rbuf/wsum/vs/pooled: 2 MB region)
    {
        float4 zz4 = {0.f, 0.f, 0.f, 0.f};
        for (int i = zb * 256 + tid; i < (2 * 1024 * 1024 / 16); i += ZB * 256)
            zreg[i] = zz4;
    }
    bool i8_0 = mask_is_i8(m0), i8_1 = mask_is_i8(m1), i8_2 = mask_is_i8(m2);
    __shared__ unsigned short wc[ZB][8];
    __shared__ int scnt[ZB], sgb[ZB], stot;
    int wave = tid >> 6;
#pragma unroll 4
    for (int zb2 = 0; zb2 < ZB; zb2++) {
        int z2 = zb2 >> 5, b2 = zb2 & 31;
        const int* mk = z2 == 0 ? m0 : (z2 == 1 ? m1 : m2);
        bool i8 = z2 == 0 ? i8_0 : (z2 == 1 ? i8_1 : i8_2);
        bool v0 = (mask_val(mk, b2 * T_S + tid, i8) == 0);
        bool v1 = (mask_val(mk, b2 * T_S + 256 + tid, i8) == 0);
        unsigned long long bl0 = __ballot(v0);
        unsigned long long bl1 = __ballot(v1);
        if ((tid & 63) == 0) {
            wc[zb2][wave] = (unsigned short)__popcll(bl0);
            wc[zb2][wave + 4] = (unsigned short)__popcll(bl1);
        }
    }
    __syncthreads();
    if (tid < ZB) {
        int s = 0;
#pragma unroll
        for (int c = 0; c < 8; c++) s += wc[tid][c];
        scnt[tid] = s;
    }
    __syncthreads();
    if (tid == 0) {
        int run = 0;
        for (int i = 0; i < ZB; i++) { sgb[i] = run; run += (scnt[i] + 63) & ~63; }
        stot = run;
    }
    __syncthreads();
    int cnt = scnt[zb], base = sgb[zb];
    if (tid == 0) {
        cnts[zb] = cnt; gb[zb] = base;
        int run = base;
#pragma unroll
        for (int c = 0; c < 8; c++) { slotbase[zb * 8 + c] = run; run += wc[zb][c]; }
        if (zb == ZB - 1) mtot[0] = stot;
    }
    int nb = (cnt + 63) >> 6;
    if (tid < nb) zblk[(base >> 6) + tid] = zb;
    // zero own pad rows [cnt, ceil64)
    int cend = (cnt + 63) & ~63;
    {
        u16* bp = xp + (size_t)(base + cnt) * D_D;
        int n8 = (cend - cnt) * (D_D / 8);
        ushort8 zz = {0,0,0,0,0,0,0,0};
        for (int i = tid; i < n8; i += 256)
            *(ushort8*)(bp + (size_t)i * 8) = zz;
    }
    if (zb == ZB - 1) {
        // global pad to 256-multiple (GEMM BM=256): zero xp rows, attnw, zblk
        int tot = stot, tend = (tot + 255) & ~255;
        u16* bp = xp + (size_t)tot * D_D;
        int n8 = (tend - tot) * (D_D / 8);
        ushort8 zz = {0,0,0,0,0,0,0,0};
        for (int i = tid; i < n8; i += 256)
            *(ushort8*)(bp + (size_t)i * 8) = zz;
        for (int i = tid; i < tend - tot; i += 256) attnw[tot + i] = 0.f;
        if (tid < ((tend - tot) >> 6)) zblk[(tot >> 6) + tid] = 0;
    }
}

// ==== k_prep: W_attn transpose (fp32) + W1 transpose (bf16) +
//      pack valid x rows as bf16 (GLOBAL slots) + masked column-sum of x ====
__global__ void k_prep(const float* __restrict__ W_attn, const float* __restrict__ W1,
                       const float* x0, const float* x1, const float* x2,
                       const int* m0, const int* m1, const int* m2,
                       const int* __restrict__ slotbase,
                       float* __restrict__ WT, u16* __restrict__ W1T,
                       float* __restrict__ xsum, u16* __restrict__ xp) {
    int bx = blockIdx.x;
    int tid = threadIdx.x;
    if (bx < 1024) {
        int tbx = bx & 31, tby = bx >> 5;
        __shared__ float tile[32][33];
        int tx = tid & 31, ty = tid >> 5;  // ty 0..7
#pragma unroll
        for (int j = 0; j < 32; j += 8)
            tile[ty + j][tx] = W_attn[(size_t)(tby*32 + ty + j)*D_D + tbx*32 + tx];
        __syncthreads();
#pragma unroll
        for (int j = 0; j < 32; j += 8)
            WT[(size_t)(tbx*32 + ty + j)*D_D + tby*32 + tx] = tile[tx][ty + j];
        __syncthreads();
#pragma unroll
        for (int j = 0; j < 32; j += 8)
            tile[ty + j][tx] = W1[(size_t)(tby*32 + ty + j)*D_D + tbx*32 + tx];
        __syncthreads();
#pragma unroll
        for (int j = 0; j < 32; j += 8)
            W1T[(size_t)(tbx*32 + ty + j)*D_D + tby*32 + tx] = f2bf(tile[tx][ty + j]);
        return;
    }
    int idx = bx - 1024;
    int chunk = idx & 7, zb = idx >> 3;
    int z = zb >> 5, b = zb & 31;
    const float* x = z == 0 ? x0 : (z == 1 ? x1 : x2);
    const int* mk = z == 0 ? m0 : (z == 1 ? m1 : m2);
    bool i8 = mask_is_i8(mk);
    int t0 = chunk * 64;
    __shared__ unsigned char s_list[64];
    __shared__ int s_cc;
    if (tid < 64) {   // exactly wave 0
        bool v = (mask_val(mk, b * T_S + t0 + tid, i8) == 0);
        unsigned long long bal = __ballot(v);
        int pos = (int)__popcll(bal & ((1ull << tid) - 1ull));
        if (v) s_list[pos] = (unsigned char)tid;
        if (tid == 0) s_cc = (int)__popcll(bal);
    }
    __syncthreads();
    int cc = s_cc;
    int slot0 = slotbase[zb * 8 + chunk];   // GLOBAL packed slot
    const float4* xr = (const float4*)(x + (size_t)(b * T_S) * D_D);
    float4 acc = {0.f, 0.f, 0.f, 0.f};
#pragma unroll 2
    for (int j = 0; j < cc; j++) {
        int t = t0 + (int)s_list[j];
        float4 v = xr[(size_t)t * 256 + tid];
        union { __hip_bfloat162 h; ushort2 u; } c0, c1;
        c0.h = __float22bfloat162_rn({v.x, v.y});
        c1.h = __float22bfloat162_rn({v.z, v.w});
        ushort4 uu = {c0.u.x, c0.u.y, c1.u.x, c1.u.y};
        *(ushort4*)(xp + (size_t)(slot0 + j) * D_D + tid * 4) = uu;
        acc.x += v.x; acc.y += v.y; acc.z += v.z; acc.w += v.w;
    }
    float* xs = xsum + (size_t)zb * D_D + tid * 4;
    atomicAdd(xs + 0, acc.x); atomicAdd(xs + 1, acc.y);
    atomicAdd(xs + 2, acc.z); atomicAdd(xs + 3, acc.w);
}

// ---- 8-way k-split batched (4 rows/block) vec@W, atomicAdd into zeroed vout ----
__global__ void k_matvec(const float* __restrict__ W, const float* __restrict__ vin,
                         const float* __restrict__ bias, const int* __restrict__ bmul,
                         float scale, float* __restrict__ vout) {
    int z = blockIdx.z, bg = blockIdx.y;
    int och = blockIdx.x >> 3, kc = blockIdx.x & 7;
    int o = och * 256 + threadIdx.x;
    int brow = z * N_B + bg * 4;
    float acc[4] = {0.f, 0.f, 0.f, 0.f};
    if (kc == 0 && bias) {
        float bv = bias[o];
#pragma unroll
        for (int bb = 0; bb < 4; bb++)
            acc[bb] = bmul ? bv * (float)bmul[brow + bb] : bv;
    }
    const float* vi = vin + (size_t)brow * D_D + kc * 128;
    const float* Wp = W + (size_t)(kc * 128) * D_D + o;
#pragma unroll 4
    for (int i = 0; i < 128; i++) {
        float wv = Wp[(size_t)i * D_D];
#pragma unroll
        for (int bb = 0; bb < 4; bb++)
            acc[bb] += vi[(size_t)bb * D_D + i] * wv;
    }
#pragma unroll
    for (int bb = 0; bb < 4; bb++)
        atomicAdd(&vout[(size_t)(brow + bb) * D_D + o], acc[bb] * scale);
}

// ---- sdot[row] = xp[row,:] . vs[zb(row),:] over globally-packed rows ----
__global__ void k_dots(const u16* __restrict__ xp, const float* __restrict__ vs,
                       const int* __restrict__ zblk, const int* __restrict__ mtot,
                       float* __restrict__ sdot) {
    int t0 = blockIdx.x * 4;
    if (t0 >= mtot[0]) return;
    int t = t0 + (threadIdx.x >> 6);
    int lane = threadIdx.x & 63;
    int zb = zblk[t0 >> 6];                 // rows 64-aligned per zb -> uniform
    const u16* xr = xp + (size_t)t * D_D;
    const float* vr = vs + (size_t)zb * D_D;
    float acc = 0.f;
#pragma unroll
    for (int i = 0; i < 2; i++) {
        short8 v = *(const short8*)(xr + i * 512 + lane * 8);
        const float* vp = vr + i * 512 + lane * 8;
        float4 a0 = *(const float4*)(vp);
        float4 a1 = *(const float4*)(vp + 4);
        acc += bf2f((u16)v[0]) * a0.x + bf2f((u16)v[1]) * a0.y
             + bf2f((u16)v[2]) * a0.z + bf2f((u16)v[3]) * a0.w
             + bf2f((u16)v[4]) * a1.x + bf2f((u16)v[5]) * a1.y
             + bf2f((u16)v[6]) * a1.z + bf2f((u16)v[7]) * a1.w;
    }
#pragma unroll
    for (int off = 32; off; off >>= 1) acc += __shfl_xor(acc, off, 64);
    if (lane == 0) sdot[t] = acc;
}

// ---- per-zb softmax over sdot[gb..gb+cnt) -> attnw (zeros in 64-pad) ----
__global__ void k_smax(const float* __restrict__ sdot, const int* __restrict__ cnts,
                       const int* __restrict__ gb, float* __restrict__ attnw) {
    int zb = blockIdx.x, tid = threadIdx.x;   // 512
    __shared__ float redm[8], reds[8];
    int cnt = cnts[zb], base = gb[zb];
    int wave = tid >> 6, lane = tid & 63;
    float v = (tid < cnt) ? sdot[base + tid] : -INFINITY;
    float mx = v;
#pragma unroll
    for (int off = 32; off; off >>= 1) mx = fmaxf(mx, __shfl_xor(mx, off, 64));
    if (lane == 0) redm[wave] = mx;
    __syncthreads();
    mx = redm[0];
#pragma unroll
    for (int k = 1; k < 8; k++) mx = fmaxf(mx, redm[k]);
    float e = __expf(v - mx);                 // exp(-inf)=0
    float es = e;
#pragma unroll
    for (int off = 32; off; off >>= 1) es += __shfl_xor(es, off, 64);
    if (lane == 0) reds[wave] = es;
    __syncthreads();
    float tot = 0.f;
#pragma unroll
    for (int k = 0; k < 8; k++) tot += reds[k];
    int cend = (cnt + 63) & ~63;
    if (tid < cend) attnw[base + tid] = (tid < cnt) ? (e / tot) : 0.f;
}

// ==== GEMM on globally-packed rows: r1's MEASURED 686 TF core (256x256 tile,
// 8 waves 2Mx4N, BK=64, 2-phase dbuf, one stage-before-MFMA + barrier/K-step)
// with: global pack (-10% FLOPs vs per-zb pad-128), attnw precomputed, and
// same-A blocks at blockIdx stride 8 -> same XCD slot -> A fetched once/XCD.
#define STAGE_TILE(buf, k0)                                                   \
    {                                                                         \
        _Pragma("unroll")                                                     \
        for (int i_ = 0; i_ < 4; i_++) {                                      \
            int r0_ = i_ * 64 + wave * 8;                                     \
            int rr_ = r0_ + srow;                                             \
            int gc_ = cp ^ srow;   /* (rr_&7)==srow since r0_%8==0 */         \
            gll16(abase + (size_t)rr_ * D_D + (k0) + gc_ * 8,                 \
                  &As[buf][r0_ * 64]);                                        \
            gll16(bbase + (size_t)rr_ * D_D + (k0) + gc_ * 8,                 \
                  &Bs[buf][r0_ * 64]);                                        \
        }                                                                     \
    }

__global__ __launch_bounds__(512, 1)
void k_gemm_bf16(const u16* __restrict__ xp, const u16* __restrict__ W1T,
                 const float* __restrict__ b1, const float* __restrict__ attnw,
                 const int* __restrict__ zblk, const int* __restrict__ mtot,
                 float* __restrict__ rbuf) {
    int bid = blockIdx.x;                     // 0..767
    int sub = bid & 31;
    int Mt = (bid >> 5) * 8 + (sub & 7);      // same Mt at bid stride 8
    int Nt = sub >> 3;
    int row0 = Mt * 256, N0 = Nt * 256;
    if (row0 >= mtot[0]) return;              // dead tile

    __shared__ __align__(16) u16 As[2][256 * 64];
    __shared__ __align__(16) u16 Bs[2][256 * 64];
    __shared__ float sAttn[256];
    int tid = threadIdx.x;
    int wave = tid >> 6, lane = tid & 63;
    if (tid < 256) sAttn[tid] = attnw[row0 + tid];

    int wy = wave >> 2, wx = wave & 3;        // 2M x 4N waves
    int q = lane >> 4, cidx = lane & 15;
    int srow = lane >> 3;        // row within an 8-row staging group
    int cp = lane & 7;           // LDS 16B-chunk position within row

    floatx4 acc[8][4];
#pragma unroll
    for (int mi = 0; mi < 8; mi++)
#pragma unroll
        for (int ni = 0; ni < 4; ni++)
            acc[mi][ni] = (floatx4){0.f, 0.f, 0.f, 0.f};

    const u16* abase = xp + (size_t)row0 * D_D;
    const u16* bbase = W1T + (size_t)N0 * D_D;

    STAGE_TILE(0, 0)
    __syncthreads();
    int cur = 0;
#pragma unroll 2
    for (int kt = 0; kt < 16; kt++) {
        if (kt < 15) { STAGE_TILE(cur ^ 1, (kt + 1) << 6) }
        __builtin_amdgcn_sched_barrier(0);    // keep prefetch issue before MFMA
#pragma unroll
        for (int ks = 0; ks < 2; ks++) {
            short8 a[8], bfr[4];
#pragma unroll
            for (int mi = 0; mi < 8; mi++) {
                int m = wy * 128 + mi * 16 + cidx;
                a[mi] = *(const short8*)&As[cur][m * 64 + ((((ks << 2) | q) ^ (m & 7)) << 3)];
            }
#pragma unroll
            for (int ni = 0; ni < 4; ni++) {
                int n = wx * 64 + ni * 16 + cidx;
                bfr[ni] = *(const short8*)&Bs[cur][n * 64 + ((((ks << 2) | q) ^ (n & 7)) << 3)];
            }
#pragma unroll
            for (int mi = 0; mi < 8; mi++)
#pragma unroll
                for (int ni = 0; ni < 4; ni++)
                    acc[mi][ni] = __builtin_amdgcn_mfma_f32_16x16x32_bf16(
                        a[mi], bfr[ni], acc[mi][ni], 0, 0, 0);
        }
        __syncthreads();                      // drains prefetch vmcnt + LDS sync
        cur ^= 1;
    }

    // epilogue: wave rows span two 64-row groups (possibly different zb)
    int zb0 = zblk[(row0 >> 6) + wy * 2];
    int zb1 = zblk[(row0 >> 6) + wy * 2 + 1];
#pragma unroll
    for (int ni = 0; ni < 4; ni++) {
        int ng = N0 + wx * 64 + ni * 16 + cidx;
        float b1v = b1[ng];
        float s0 = 0.f, s1 = 0.f;
#pragma unroll
        for (int mi = 0; mi < 8; mi++) {
            float part = 0.f;
#pragma unroll
            for (int rg = 0; rg < 4; rg++) {
                int ml = wy * 128 + mi * 16 + q * 4 + rg;
                float hv = fmaxf(acc[mi][ni][rg] + b1v, 0.f);
                part += hv * sAttn[ml];
            }
            if (mi < 4) s0 += part; else s1 += part;
        }
        s0 += __shfl_xor(s0, 16, 64); s0 += __shfl_xor(s0, 32, 64);
        s1 += __shfl_xor(s1, 16, 64); s1 += __shfl_xor(s1, 32, 64);
        if (lane < 16) {
            atomicAdd(&rbuf[(size_t)zb0 * D_D + ng], s0);
            atomicAdd(&rbuf[(size_t)zb1 * D_D + ng], s1);
        }
    }
}

// ==== k_fin: LayerNorm + relu + (1024x120) classifier, 512 threads ====
__global__ void k_fin(const float* __restrict__ pooled, const float* __restrict__ ln_g,
                      const float* __restrict__ ln_b, const float* __restrict__ Wl,
                      const float* __restrict__ bl, float* __restrict__ out) {
    int zb = blockIdx.x;
    int tid = threadIdx.x;  // 512
    __shared__ float nr[D_D];
    __shared__ float redA[8], redB[8];
    __shared__ float ps[4][C_C];
    const float* p = pooled + (size_t)zb * D_D;
    int o0 = tid, o1 = tid + 512;
    float a0 = p[o0], a1 = p[o1];
    float s1 = a0 + a1, s2 = a0 * a0 + a1 * a1;
#pragma unroll
    for (int off = 32; off; off >>= 1) {
        s1 += __shfl_xor(s1, off, 64);
        s2 += __shfl_xor(s2, off, 64);
    }
    int w = tid >> 6;
    if ((tid & 63) == 0) { redA[w] = s1; redB[w] = s2; }
    __syncthreads();
    float t1 = 0.f, t2 = 0.f;
#pragma unroll
    for (int k = 0; k < 8; k++) { t1 += redA[k]; t2 += redB[k]; }
    float mu = t1 * (1.0f / D_D);
    float var = t2 * (1.0f / D_D) - mu * mu;
    float rstd = 1.0f / sqrtf(var + 1e-12f);
    nr[o0] = fmaxf((a0 - mu) * rstd * ln_g[o0] + ln_b[o0], 0.f);
    nr[o1] = fmaxf((a1 - mu) * rstd * ln_g[o1] + ln_b[o1], 0.f);
    __syncthreads();
    if (tid < 4 * C_C) {
        int seg = tid / C_C, c = tid - seg * C_C;
        const float* wp = Wl + (size_t)(seg * 256) * C_C + c;
        const float* np = nr + seg * 256;
        float acc = 0.f;
#pragma unroll 8
        for (int d = 0; d < 256; d++)
            acc += np[d] * wp[(size_t)d * C_C];
        ps[seg][c] = acc;
    }
    __syncthreads();
    if (tid < C_C)
        out[(size_t)zb * C_C + tid] =
            bl[tid] + ps[0][tid] + ps[1][tid] + ps[2][tid] + ps[3][tid];
}

extern "C" void kernel_launch(void* const* d_in, const int* in_sizes, int n_in,
                              void* d_out, int out_size, void* d_ws, size_t ws_size,
                              hipStream_t stream) {
    const float* x0 = (const float*)d_in[0];
    const float* x1 = (const float*)d_in[1];
    const float* x2 = (const float*)d_in[2];
    const int* m0 = (const int*)d_in[3];
    const int* m1 = (const int*)d_in[4];
    const int* m2 = (const int*)d_in[5];
    const float* W_attn = (const float*)d_in[6];
    const float* b_attn = (const float*)d_in[7];
    const float* W1 = (const float*)d_in[8];
    const float* b1 = (const float*)d_in[9];
    const float* W2 = (const float*)d_in[10];
    const float* b2 = (const float*)d_in[11];
    const float* ln_g = (const float*)d_in[12];
    const float* ln_b = (const float*)d_in[13];
    const float* W_last = (const float*)d_in[14];
    const float* b_last = (const float*)d_in[15];
    float* out = (float*)d_out;

    char* wsb = (char*)d_ws;
    const size_t MB = 1 << 20;
    float* WT     = (float*)(wsb);                    // 4 MB
    u16*   W1T    = (u16*)  (wsb + 4 * MB);           // 2 MB
    // zeroed region (by k_scan): 6MB..8MB
    float* xsum   = (float*)(wsb + 6 * MB);           // 384 KB
    float* rbuf   = (float*)(wsb + 6 * MB + 393216);  // 384 KB
    float* wsum   = (float*)(wsb + 6 * MB + 786432);  // 384 KB
    float* vs     = (float*)(wsb + 6 * MB + 1179648); // 384 KB
    float* pooled = (float*)(wsb + 6 * MB + 1572864); // 384 KB
    // non-zeroed
    float* sdot   = (float*)(wsb + 8 * MB);           // 192 KB (global rows)
    float* attnw  = (float*)(wsb + 8 * MB + 196608);  // 192 KB (global rows)
    int*   slotb  = (int*)  (wsb + 8 * MB + 393216);  // 3 KB
    int*   cnts   = (int*)  (wsb + 8 * MB + 397312);  // 384 B
    int*   gb     = (int*)  (wsb + 8 * MB + 401408);  // 384 B
    int*   mtot   = (int*)  (wsb + 8 * MB + 405504);  // 4 B
    int*   zblk   = (int*)  (wsb + 8 * MB + 409600);  // 3.1 KB
    u16*   xp     = (u16*)  (wsb + 9 * MB);           // 96 MB packed bf16 x

    k_scan  <<<ZB, 256, 0, stream>>>(m0, m1, m2, slotb, cnts, gb, zblk, mtot,
                                     xp, attnw, (float4*)(wsb + 6 * MB));
    k_prep  <<<1792, 256, 0, stream>>>(W_attn, W1, x0, x1, x2, m0, m1, m2,
                                       slotb, WT, W1T, xsum, xp);
    // wsum = xsum@W_attn + cnt*b_attn
    k_matvec<<<dim3(32, 8, 3), 256, 0, stream>>>(W_attn, xsum, b_attn, cnts, 1.0f, wsum);
    // vs = (W_attn . wsum)/SCALE  via transposed weights
    k_matvec<<<dim3(32, 8, 3), 256, 0, stream>>>(WT, wsum, nullptr, nullptr, 1.0f / SCALE, vs);
    k_dots  <<<12288, 256, 0, stream>>>(xp, vs, zblk, mtot, sdot);
    k_smax  <<<ZB, 512, 0, stream>>>(sdot, cnts, gb, attnw);
    k_gemm_bf16<<<768, 512, 0, stream>>>(xp, W1T, b1, attnw, zblk, mtot, rbuf);
    // pooled = rbuf@W2 + b2  (k_matvec reuse: 4-zb batching)
    k_matvec<<<dim3(32, 8, 3), 256, 0, stream>>>(W2, rbuf, b2, nullptr, 1.0f, pooled);
    k_fin   <<<ZB, 512, 0, stream>>>(pooled, ln_g, ln_b, W_last, b_last, out);
}

// Round 6
// 370.150 us; speedup vs baseline: 1.0969x; 1.0969x over previous
//
#include <hip/hip_runtime.h>
#include <hip/hip_bf16.h>
#include <math.h>

#define N_B 32
#define T_S 512
#define D_D 1024
#define C_C 120
#define ZB 96           // 3 streams x 32 batch rows
#define SCALE 64.0f     // 2*sqrt(1024)

typedef unsigned short u16;
typedef __attribute__((ext_vector_type(8))) short short8;
typedef __attribute__((ext_vector_type(8))) unsigned short ushort8;
typedef __attribute__((ext_vector_type(4))) float floatx4;

__device__ inline u16 f2bf(float f) {
    union { __hip_bfloat16 h; u16 u; } c; c.h = __float2bfloat16(f); return c.u;
}
__device__ inline float bf2f(u16 u) {
    union { unsigned i; float f; } c; c.i = ((unsigned)u) << 16; return c.f;
}

// async global->LDS, 16B per lane. LDS dest = wave-uniform base + lane*16.
__device__ inline void gll16(const void* g, void* l) {
    __builtin_amdgcn_global_load_lds((const __attribute__((address_space(1))) void*)g,
                                     (__attribute__((address_space(3))) void*)l,
                                     16, 0, 0);
}

// ---- mask dtype robustness: harness may deliver bool as int32 or int8 ----
__device__ inline bool mask_is_i8(const int* mk) {
    bool i8 = false;
#pragma unroll
    for (int i = 0; i < 16; i++) {
        unsigned v = ((const unsigned*)mk)[i];
        if (v > 1u) i8 = true;
    }
    return i8;
}
__device__ inline int mask_val(const int* mk, int idx, bool i8) {
    return i8 ? (int)((const signed char*)mk)[idx] : mk[idx];
}

// ==== k_scan: wave-parallel redundant count of ALL 96 zb rows, so every block
// derives its own zb's GLOBAL packed base (pad-64) with no cross-block dep.
// 512 threads = 8 waves; wave w counts zb rows [w*12, w*12+12): lane l loads 8
// mask values, 3x shfl_xor segmented-sum over 8-lane groups -> per-chunk counts.
// Serial chain: 12 dependent loads (was 96 serial ballot iters in r5, ~30us).
// Writes slotbase/cnts/gb/zblk/mtot; zeroes pad rows + 2MB accumulator region.
__global__ __launch_bounds__(512)
void k_scan(const int* m0, const int* m1, const int* m2,
            int* __restrict__ slotbase, int* __restrict__ cnts,
            int* __restrict__ gb, int* __restrict__ zblk,
            int* __restrict__ mtot, u16* __restrict__ xp,
            float* __restrict__ attnw, float4* __restrict__ zreg) {
    int zb = blockIdx.x;
    int tid = threadIdx.x;
    // zero accumulators (xsum/rbuf/wsum/vs/pooled: 2 MB region)
    {
        float4 zz4 = {0.f, 0.f, 0.f, 0.f};
        for (int i = zb * 512 + tid; i < (2 * 1024 * 1024 / 16); i += ZB * 512)
            zreg[i] = zz4;
    }
    bool i8_0 = mask_is_i8(m0), i8_1 = mask_is_i8(m1), i8_2 = mask_is_i8(m2);
    __shared__ unsigned short wc[ZB][8];
    __shared__ int scnt[ZB], sgb[ZB], stot;
    int wave = tid >> 6, lane = tid & 63;
#pragma unroll
    for (int it = 0; it < 12; it++) {
        int zb2 = wave * 12 + it;
        int z2 = zb2 >> 5, b2 = zb2 & 31;
        const int* mk = z2 == 0 ? m0 : (z2 == 1 ? m1 : m2);
        bool i8 = z2 == 0 ? i8_0 : (z2 == 1 ? i8_1 : i8_2);
        int c = 0;
        if (i8) {
            const signed char* p = (const signed char*)mk + b2 * T_S + lane * 8;
#pragma unroll
            for (int e = 0; e < 8; e++) c += (p[e] == 0);
        } else {
            const int* p = mk + b2 * T_S + lane * 8;
#pragma unroll
            for (int e = 0; e < 8; e++) c += (p[e] == 0);
        }
        // sum within each 8-lane group (= one 64-t chunk)
        c += __shfl_xor(c, 1, 64);
        c += __shfl_xor(c, 2, 64);
        c += __shfl_xor(c, 4, 64);
        if ((lane & 7) == 0) wc[zb2][lane >> 3] = (unsigned short)c;
    }
    __syncthreads();
    if (tid < ZB) {
        int s = 0;
#pragma unroll
        for (int c = 0; c < 8; c++) s += wc[tid][c];
        scnt[tid] = s;
    }
    __syncthreads();
    if (tid == 0) {
        int run = 0;
        for (int i = 0; i < ZB; i++) { sgb[i] = run; run += (scnt[i] + 63) & ~63; }
        stot = run;
    }
    __syncthreads();
    int cnt = scnt[zb], base = sgb[zb];
    if (tid == 0) {
        cnts[zb] = cnt; gb[zb] = base;
        int run = base;
#pragma unroll
        for (int c = 0; c < 8; c++) { slotbase[zb * 8 + c] = run; run += wc[zb][c]; }
        if (zb == ZB - 1) mtot[0] = stot;
    }
    int nb = (cnt + 63) >> 6;
    if (tid < nb) zblk[(base >> 6) + tid] = zb;
    // zero own pad rows [cnt, ceil64)
    int cend = (cnt + 63) & ~63;
    {
        u16* bp = xp + (size_t)(base + cnt) * D_D;
        int n8 = (cend - cnt) * (D_D / 8);
        ushort8 zz = {0,0,0,0,0,0,0,0};
        for (int i = tid; i < n8; i += 512)
            *(ushort8*)(bp + (size_t)i * 8) = zz;
    }
    if (zb == ZB - 1) {
        // global pad to 256-multiple (GEMM BM=256): zero xp rows, attnw, zblk
        int tot = stot, tend = (tot + 255) & ~255;
        u16* bp = xp + (size_t)tot * D_D;
        int n8 = (tend - tot) * (D_D / 8);
        ushort8 zz = {0,0,0,0,0,0,0,0};
        for (int i = tid; i < n8; i += 512)
            *(ushort8*)(bp + (size_t)i * 8) = zz;
        for (int i = tid; i < tend - tot; i += 512) attnw[tot + i] = 0.f;
        if (tid < ((tend - tot) >> 6)) zblk[(tot >> 6) + tid] = 0;
    }
}

// ==== k_prep: W_attn transpose (fp32) + W1 transpose (bf16) +
//      pack valid x rows as bf16 (GLOBAL slots) + masked column-sum of x ====
__global__ void k_prep(const float* __restrict__ W_attn, const float* __restrict__ W1,
                       const float* x0, const float* x1, const float* x2,
                       const int* m0, const int* m1, const int* m2,
                       const int* __restrict__ slotbase,
                       float* __restrict__ WT, u16* __restrict__ W1T,
                       float* __restrict__ xsum, u16* __restrict__ xp) {
    int bx = blockIdx.x;
    int tid = threadIdx.x;
    if (bx < 1024) {
        int tbx = bx & 31, tby = bx >> 5;
        __shared__ float tile[32][33];
        int tx = tid & 31, ty = tid >> 5;  // ty 0..7
#pragma unroll
        for (int j = 0; j < 32; j += 8)
            tile[ty + j][tx] = W_attn[(size_t)(tby*32 + ty + j)*D_D + tbx*32 + tx];
        __syncthreads();
#pragma unroll
        for (int j = 0; j < 32; j += 8)
            WT[(size_t)(tbx*32 + ty + j)*D_D + tby*32 + tx] = tile[tx][ty + j];
        __syncthreads();
#pragma unroll
        for (int j = 0; j < 32; j += 8)
            tile[ty + j][tx] = W1[(size_t)(tby*32 + ty + j)*D_D + tbx*32 + tx];
        __syncthreads();
#pragma unroll
        for (int j = 0; j < 32; j += 8)
            W1T[(size_t)(tbx*32 + ty + j)*D_D + tby*32 + tx] = f2bf(tile[tx][ty + j]);
        return;
    }
    int idx = bx - 1024;
    int chunk = idx & 7, zb = idx >> 3;
    int z = zb >> 5, b = zb & 31;
    const float* x = z == 0 ? x0 : (z == 1 ? x1 : x2);
    const int* mk = z == 0 ? m0 : (z == 1 ? m1 : m2);
    bool i8 = mask_is_i8(mk);
    int t0 = chunk * 64;
    __shared__ unsigned char s_list[64];
    __shared__ int s_cc;
    if (tid < 64) {   // exactly wave 0
        bool v = (mask_val(mk, b * T_S + t0 + tid, i8) == 0);
        unsigned long long bal = __ballot(v);
        int pos = (int)__popcll(bal & ((1ull << tid) - 1ull));
        if (v) s_list[pos] = (unsigned char)tid;
        if (tid == 0) s_cc = (int)__popcll(bal);
    }
    __syncthreads();
    int cc = s_cc;
    int slot0 = slotbase[zb * 8 + chunk];   // GLOBAL packed slot
    const float4* xr = (const float4*)(x + (size_t)(b * T_S) * D_D);
    float4 acc = {0.f, 0.f, 0.f, 0.f};
#pragma unroll 2
    for (int j = 0; j < cc; j++) {
        int t = t0 + (int)s_list[j];
        float4 v = xr[(size_t)t * 256 + tid];
        union { __hip_bfloat162 h; ushort2 u; } c0, c1;
        c0.h = __float22bfloat162_rn({v.x, v.y});
        c1.h = __float22bfloat162_rn({v.z, v.w});
        ushort4 uu = {c0.u.x, c0.u.y, c1.u.x, c1.u.y};
        *(ushort4*)(xp + (size_t)(slot0 + j) * D_D + tid * 4) = uu;
        acc.x += v.x; acc.y += v.y; acc.z += v.z; acc.w += v.w;
    }
    float* xs = xsum + (size_t)zb * D_D + tid * 4;
    atomicAdd(xs + 0, acc.x); atomicAdd(xs + 1, acc.y);
    atomicAdd(xs + 2, acc.z); atomicAdd(xs + 3, acc.w);
}

// ---- 8-way k-split batched (4 rows/block) vec@W, atomicAdd into zeroed vout ----
__global__ void k_matvec(const float* __restrict__ W, const float* __restrict__ vin,
                         const float* __restrict__ bias, const int* __restrict__ bmul,
                         float scale, float* __restrict__ vout) {
    int z = blockIdx.z, bg = blockIdx.y;
    int och = blockIdx.x >> 3, kc = blockIdx.x & 7;
    int o = och * 256 + threadIdx.x;
    int brow = z * N_B + bg * 4;
    float acc[4] = {0.f, 0.f, 0.f, 0.f};
    if (kc == 0 && bias) {
        float bv = bias[o];
#pragma unroll
        for (int bb = 0; bb < 4; bb++)
            acc[bb] = bmul ? bv * (float)bmul[brow + bb] : bv;
    }
    const float* vi = vin + (size_t)brow * D_D + kc * 128;
    const float* Wp = W + (size_t)(kc * 128) * D_D + o;
#pragma unroll 4
    for (int i = 0; i < 128; i++) {
        float wv = Wp[(size_t)i * D_D];
#pragma unroll
        for (int bb = 0; bb < 4; bb++)
            acc[bb] += vi[(size_t)bb * D_D + i] * wv;
    }
#pragma unroll
    for (int bb = 0; bb < 4; bb++)
        atomicAdd(&vout[(size_t)(brow + bb) * D_D + o], acc[bb] * scale);
}

// ---- sdot[row] = xp[row,:] . vs[zb(row),:] over globally-packed rows ----
__global__ void k_dots(const u16* __restrict__ xp, const float* __restrict__ vs,
                       const int* __restrict__ zblk, const int* __restrict__ mtot,
                       float* __restrict__ sdot) {
    int t0 = blockIdx.x * 4;
    if (t0 >= mtot[0]) return;
    int t = t0 + (threadIdx.x >> 6);
    int lane = threadIdx.x & 63;
    int zb = zblk[t0 >> 6];                 // rows 64-aligned per zb -> uniform
    const u16* xr = xp + (size_t)t * D_D;
    const float* vr = vs + (size_t)zb * D_D;
    float acc = 0.f;
#pragma unroll
    for (int i = 0; i < 2; i++) {
        short8 v = *(const short8*)(xr + i * 512 + lane * 8);
        const float* vp = vr + i * 512 + lane * 8;
        float4 a0 = *(const float4*)(vp);
        float4 a1 = *(const float4*)(vp + 4);
        acc += bf2f((u16)v[0]) * a0.x + bf2f((u16)v[1]) * a0.y
             + bf2f((u16)v[2]) * a0.z + bf2f((u16)v[3]) * a0.w
             + bf2f((u16)v[4]) * a1.x + bf2f((u16)v[5]) * a1.y
             + bf2f((u16)v[6]) * a1.z + bf2f((u16)v[7]) * a1.w;
    }
#pragma unroll
    for (int off = 32; off; off >>= 1) acc += __shfl_xor(acc, off, 64);
    if (lane == 0) sdot[t] = acc;
}

// ---- per-zb softmax over sdot[gb..gb+cnt) -> attnw (zeros in 64-pad) ----
__global__ void k_smax(const float* __restrict__ sdot, const int* __restrict__ cnts,
                       const int* __restrict__ gb, float* __restrict__ attnw) {
    int zb = blockIdx.x, tid = threadIdx.x;   // 512
    __shared__ float redm[8], reds[8];
    int cnt = cnts[zb], base = gb[zb];
    int wave = tid >> 6, lane = tid & 63;
    float v = (tid < cnt) ? sdot[base + tid] : -INFINITY;
    float mx = v;
#pragma unroll
    for (int off = 32; off; off >>= 1) mx = fmaxf(mx, __shfl_xor(mx, off, 64));
    if (lane == 0) redm[wave] = mx;
    __syncthreads();
    mx = redm[0];
#pragma unroll
    for (int k = 1; k < 8; k++) mx = fmaxf(mx, redm[k]);
    float e = __expf(v - mx);                 // exp(-inf)=0
    float es = e;
#pragma unroll
    for (int off = 32; off; off >>= 1) es += __shfl_xor(es, off, 64);
    if (lane == 0) reds[wave] = es;
    __syncthreads();
    float tot = 0.f;
#pragma unroll
    for (int k = 0; k < 8; k++) tot += reds[k];
    int cend = (cnt + 63) & ~63;
    if (tid < cend) attnw[base + tid] = (tid < cnt) ? (e / tot) : 0.f;
}

// ==== GEMM on globally-packed rows: r5 MEASURED 69.6us / 833 TF core.
// 256x256 tile, 8 waves 2Mx4N, BK=64, 2-phase dbuf, stage-before-MFMA,
// one barrier pair per K-step; same-A blocks at bid stride 8 (same XCD).
// UNTOUCHED this round.
#define STAGE_TILE(buf, k0)                                                   \
    {                                                                         \
        _Pragma("unroll")                                                     \
        for (int i_ = 0; i_ < 4; i_++) {                                      \
            int r0_ = i_ * 64 + wave * 8;                                     \
            int rr_ = r0_ + srow;                                             \
            int gc_ = cp ^ srow;   /* (rr_&7)==srow since r0_%8==0 */         \
            gll16(abase + (size_t)rr_ * D_D + (k0) + gc_ * 8,                 \
                  &As[buf][r0_ * 64]);                                        \
            gll16(bbase + (size_t)rr_ * D_D + (k0) + gc_ * 8,                 \
                  &Bs[buf][r0_ * 64]);                                        \
        }                                                                     \
    }

__global__ __launch_bounds__(512, 1)
void k_gemm_bf16(const u16* __restrict__ xp, const u16* __restrict__ W1T,
                 const float* __restrict__ b1, const float* __restrict__ attnw,
                 const int* __restrict__ zblk, const int* __restrict__ mtot,
                 float* __restrict__ rbuf) {
    int bid = blockIdx.x;                     // 0..767
    int sub = bid & 31;
    int Mt = (bid >> 5) * 8 + (sub & 7);      // same Mt at bid stride 8
    int Nt = sub >> 3;
    int row0 = Mt * 256, N0 = Nt * 256;
    if (row0 >= mtot[0]) return;              // dead tile

    __shared__ __align__(16) u16 As[2][256 * 64];
    __shared__ __align__(16) u16 Bs[2][256 * 64];
    __shared__ float sAttn[256];
    int tid = threadIdx.x;
    int wave = tid >> 6, lane = tid & 63;
    if (tid < 256) sAttn[tid] = attnw[row0 + tid];

    int wy = wave >> 2, wx = wave & 3;        // 2M x 4N waves
    int q = lane >> 4, cidx = lane & 15;
    int srow = lane >> 3;        // row within an 8-row staging group
    int cp = lane & 7;           // LDS 16B-chunk position within row

    floatx4 acc[8][4];
#pragma unroll
    for (int mi = 0; mi < 8; mi++)
#pragma unroll
        for (int ni = 0; ni < 4; ni++)
            acc[mi][ni] = (floatx4){0.f, 0.f, 0.f, 0.f};

    const u16* abase = xp + (size_t)row0 * D_D;
    const u16* bbase = W1T + (size_t)N0 * D_D;

    STAGE_TILE(0, 0)
    __syncthreads();
    int cur = 0;
#pragma unroll 2
    for (int kt = 0; kt < 16; kt++) {
        if (kt < 15) { STAGE_TILE(cur ^ 1, (kt + 1) << 6) }
        __builtin_amdgcn_sched_barrier(0);    // keep prefetch issue before MFMA
#pragma unroll
        for (int ks = 0; ks < 2; ks++) {
            short8 a[8], bfr[4];
#pragma unroll
            for (int mi = 0; mi < 8; mi++) {
                int m = wy * 128 + mi * 16 + cidx;
                a[mi] = *(const short8*)&As[cur][m * 64 + ((((ks << 2) | q) ^ (m & 7)) << 3)];
            }
#pragma unroll
            for (int ni = 0; ni < 4; ni++) {
                int n = wx * 64 + ni * 16 + cidx;
                bfr[ni] = *(const short8*)&Bs[cur][n * 64 + ((((ks << 2) | q) ^ (n & 7)) << 3)];
            }
#pragma unroll
            for (int mi = 0; mi < 8; mi++)
#pragma unroll
                for (int ni = 0; ni < 4; ni++)
                    acc[mi][ni] = __builtin_amdgcn_mfma_f32_16x16x32_bf16(
                        a[mi], bfr[ni], acc[mi][ni], 0, 0, 0);
        }
        __syncthreads();                      // drains prefetch vmcnt + LDS sync
        cur ^= 1;
    }

    // epilogue: wave rows span two 64-row groups (possibly different zb)
    int zb0 = zblk[(row0 >> 6) + wy * 2];
    int zb1 = zblk[(row0 >> 6) + wy * 2 + 1];
#pragma unroll
    for (int ni = 0; ni < 4; ni++) {
        int ng = N0 + wx * 64 + ni * 16 + cidx;
        float b1v = b1[ng];
        float s0 = 0.f, s1 = 0.f;
#pragma unroll
        for (int mi = 0; mi < 8; mi++) {
            float part = 0.f;
#pragma unroll
            for (int rg = 0; rg < 4; rg++) {
                int ml = wy * 128 + mi * 16 + q * 4 + rg;
                float hv = fmaxf(acc[mi][ni][rg] + b1v, 0.f);
                part += hv * sAttn[ml];
            }
            if (mi < 4) s0 += part; else s1 += part;
        }
        s0 += __shfl_xor(s0, 16, 64); s0 += __shfl_xor(s0, 32, 64);
        s1 += __shfl_xor(s1, 16, 64); s1 += __shfl_xor(s1, 32, 64);
        if (lane < 16) {
            atomicAdd(&rbuf[(size_t)zb0 * D_D + ng], s0);
            atomicAdd(&rbuf[(size_t)zb1 * D_D + ng], s1);
        }
    }
}

// ==== k_fin: LayerNorm + relu + (1024x120) classifier, 512 threads ====
__global__ void k_fin(const float* __restrict__ pooled, const float* __restrict__ ln_g,
                      const float* __restrict__ ln_b, const float* __restrict__ Wl,
                      const float* __restrict__ bl, float* __restrict__ out) {
    int zb = blockIdx.x;
    int tid = threadIdx.x;  // 512
    __shared__ float nr[D_D];
    __shared__ float redA[8], redB[8];
    __shared__ float ps[4][C_C];
    const float* p = pooled + (size_t)zb * D_D;
    int o0 = tid, o1 = tid + 512;
    float a0 = p[o0], a1 = p[o1];
    float s1 = a0 + a1, s2 = a0 * a0 + a1 * a1;
#pragma unroll
    for (int off = 32; off; off >>= 1) {
        s1 += __shfl_xor(s1, off, 64);
        s2 += __shfl_xor(s2, off, 64);
    }
    int w = tid >> 6;
    if ((tid & 63) == 0) { redA[w] = s1; redB[w] = s2; }
    __syncthreads();
    float t1 = 0.f, t2 = 0.f;
#pragma unroll
    for (int k = 0; k < 8; k++) { t1 += redA[k]; t2 += redB[k]; }
    float mu = t1 * (1.0f / D_D);
    float var = t2 * (1.0f / D_D) - mu * mu;
    float rstd = 1.0f / sqrtf(var + 1e-12f);
    nr[o0] = fmaxf((a0 - mu) * rstd * ln_g[o0] + ln_b[o0], 0.f);
    nr[o1] = fmaxf((a1 - mu) * rstd * ln_g[o1] + ln_b[o1], 0.f);
    __syncthreads();
    if (tid < 4 * C_C) {
        int seg = tid / C_C, c = tid - seg * C_C;
        const float* wp = Wl + (size_t)(seg * 256) * C_C + c;
        const float* np = nr + seg * 256;
        float acc = 0.f;
#pragma unroll 8
        for (int d = 0; d < 256; d++)
            acc += np[d] * wp[(size_t)d * C_C];
        ps[seg][c] = acc;
    }
    __syncthreads();
    if (tid < C_C)
        out[(size_t)zb * C_C + tid] =
            bl[tid] + ps[0][tid] + ps[1][tid] + ps[2][tid] + ps[3][tid];
}

extern "C" void kernel_launch(void* const* d_in, const int* in_sizes, int n_in,
                              void* d_out, int out_size, void* d_ws, size_t ws_size,
                              hipStream_t stream) {
    const float* x0 = (const float*)d_in[0];
    const float* x1 = (const float*)d_in[1];
    const float* x2 = (const float*)d_in[2];
    const int* m0 = (const int*)d_in[3];
    const int* m1 = (const int*)d_in[4];
    const int* m2 = (const int*)d_in[5];
    const float* W_attn = (const float*)d_in[6];
    const float* b_attn = (const float*)d_in[7];
    const float* W1 = (const float*)d_in[8];
    const float* b1 = (const float*)d_in[9];
    const float* W2 = (const float*)d_in[10];
    const float* b2 = (const float*)d_in[11];
    const float* ln_g = (const float*)d_in[12];
    const float* ln_b = (const float*)d_in[13];
    const float* W_last = (const float*)d_in[14];
    const float* b_last = (const float*)d_in[15];
    float* out = (float*)d_out;

    char* wsb = (char*)d_ws;
    const size_t MB = 1 << 20;
    float* WT     = (float*)(wsb);                    // 4 MB
    u16*   W1T    = (u16*)  (wsb + 4 * MB);           // 2 MB
    // zeroed region (by k_scan): 6MB..8MB
    float* xsum   = (float*)(wsb + 6 * MB);           // 384 KB
    float* rbuf   = (float*)(wsb + 6 * MB + 393216);  // 384 KB
    float* wsum   = (float*)(wsb + 6 * MB + 786432);  // 384 KB
    float* vs     = (float*)(wsb + 6 * MB + 1179648); // 384 KB
    float* pooled = (float*)(wsb + 6 * MB + 1572864); // 384 KB
    // non-zeroed (roomy slots: worst-case mtot = 96*512 rows)
    float* sdot   = (float*)(wsb + 8 * MB);           // 256 KB slot
    float* attnw  = (float*)(wsb + 8 * MB + 262144);  // 256 KB slot
    int*   slotb  = (int*)  (wsb + 8 * MB + 524288);  // 3 KB
    int*   cnts   = (int*)  (wsb + 8 * MB + 528384);  // 384 B
    int*   gb     = (int*)  (wsb + 8 * MB + 532480);  // 384 B
    int*   mtot   = (int*)  (wsb + 8 * MB + 536576);  // 4 B
    int*   zblk   = (int*)  (wsb + 8 * MB + 540672);  // 4 KB
    u16*   xp     = (u16*)  (wsb + 9 * MB);           // 96 MB packed bf16 x

    k_scan  <<<ZB, 512, 0, stream>>>(m0, m1, m2, slotb, cnts, gb, zblk, mtot,
                                     xp, attnw, (float4*)(wsb + 6 * MB));
    k_prep  <<<1792, 256, 0, stream>>>(W_attn, W1, x0, x1, x2, m0, m1, m2,
                                       slotb, WT, W1T, xsum, xp);
    // wsum = xsum@W_attn + cnt*b_attn
    k_matvec<<<dim3(32, 8, 3), 256, 0, stream>>>(W_attn, xsum, b_attn, cnts, 1.0f, wsum);
    // vs = (W_attn . wsum)/SCALE  via transposed weights
    k_matvec<<<dim3(32, 8, 3), 256, 0, stream>>>(WT, wsum, nullptr, nullptr, 1.0f / SCALE, vs);
    k_dots  <<<12288, 256, 0, stream>>>(xp, vs, zblk, mtot, sdot);
    k_smax  <<<ZB, 512, 0, stream>>>(sdot, cnts, gb, attnw);
    k_gemm_bf16<<<768, 512, 0, stream>>>(xp, W1T, b1, attnw, zblk, mtot, rbuf);
    // pooled = rbuf@W2 + b2  (k_matvec reuse: 4-zb batching)
    k_matvec<<<dim3(32, 8, 3), 256, 0, stream>>>(W2, rbuf, b2, nullptr, 1.0f, pooled);
    k_fin   <<<ZB, 512, 0, stream>>>(pooled, ln_g, ln_b, W_last, b_last, out);
}